// Round 1
// baseline (462.185 us; speedup 1.0000x reference)
//
#include <hip/hip_runtime.h>

// ---- problem constants ----
#define Bq   4
#define Sq   2048
#define Eq   1024
#define Hq   16
#define HDq  64
#define Mq   (Bq*Sq)       // 8192
#define N1q  (3*Eq)        // 3072
#define Kq   Eq            // 1024

typedef __bf16 bf16x8 __attribute__((ext_vector_type(8)));
typedef __bf16 bf16x4 __attribute__((ext_vector_type(4)));
typedef float  f32x4  __attribute__((ext_vector_type(4)));

#define GAS __attribute__((address_space(1)))
#define LAS __attribute__((address_space(3)))

__device__ __forceinline__ void gl2lds16(const void* g, void* l) {
  // async global->LDS, 16B per lane; LDS dest = wave-uniform base + lane*16
  __builtin_amdgcn_global_load_lds((GAS const void*)g, (LAS void*)l, 16, 0, 0);
}

// ---------------- fp32 -> bf16 convert (float4 vectorized) ----------------
__global__ __launch_bounds__(256) void cvt4(const float* __restrict__ in,
                                            __bf16* __restrict__ out, int n4) {
  int i = blockIdx.x * 256 + threadIdx.x;
  if (i >= n4) return;
  float4 v = ((const float4*)in)[i];
  bf16x4 o = { (__bf16)v.x, (__bf16)v.y, (__bf16)v.z, (__bf16)v.w };
  ((bf16x4*)out)[i] = o;
}

// ---------------- GEMM  C = A(MxK) * B(NxK)^T  (both K-major, bf16) ------
// MODE 0: write bf16 C to qkv_out[m*N+n]
// MODE 1: write fp32 C + bias to out[m*N+n]
template <int MODE>
__global__ __launch_bounds__(256) void gemm_bt(const __bf16* __restrict__ A,
                                               const __bf16* __restrict__ Bw,
                                               int N, int K,
                                               __bf16* __restrict__ cbf,
                                               const float* __restrict__ bias,
                                               float* __restrict__ cf32) {
  __shared__ __align__(16) __bf16 As[128 * 32];
  __shared__ __align__(16) __bf16 Bs[128 * 32];
  const int tid  = threadIdx.x;
  const int wave = tid >> 6, lane = tid & 63;
  const int quad = lane >> 4, l15 = lane & 15;
  const int wm = wave & 1, wn = wave >> 1;       // 2x2 wave grid, 64x64 each
  const int bm0 = blockIdx.x * 128;
  const int bn0 = blockIdx.y * 128;

  f32x4 acc[4][4] = {};

  // staging: thread t covers LDS slot t*16B (row t/4, col-chunk (t&3)*8) and slot (t+256)*16B
  const int ar = tid >> 2, ac = (tid & 3) * 8;
  const __bf16* Ag0 = A  + (long)(bm0 + ar) * K + ac;
  const __bf16* Bg0 = Bw + (long)(bn0 + ar) * K + ac;
  __bf16* As0 = As + wave * 512; __bf16* As1 = As + 2048 + wave * 512;
  __bf16* Bs0 = Bs + wave * 512; __bf16* Bs1 = Bs + 2048 + wave * 512;

  for (int kc = 0; kc < K; kc += 32) {
    gl2lds16(Ag0 + kc,          As0);
    gl2lds16(Ag0 + 64 * K + kc, As1);
    gl2lds16(Bg0 + kc,          Bs0);
    gl2lds16(Bg0 + 64 * K + kc, Bs1);
    __syncthreads();   // drains vmcnt -> LDS tiles ready

    bf16x8 af[4], bfr[4];
#pragma unroll
    for (int mt = 0; mt < 4; mt++)
      af[mt] = *(const bf16x8*)&As[(wm * 64 + mt * 16 + l15) * 32 + quad * 8];
#pragma unroll
    for (int nt = 0; nt < 4; nt++)
      bfr[nt] = *(const bf16x8*)&Bs[(wn * 64 + nt * 16 + l15) * 32 + quad * 8];
#pragma unroll
    for (int mt = 0; mt < 4; mt++)
#pragma unroll
      for (int nt = 0; nt < 4; nt++)
        acc[mt][nt] = __builtin_amdgcn_mfma_f32_16x16x32_bf16(af[mt], bfr[nt], acc[mt][nt], 0, 0, 0);
    __syncthreads();   // all waves done reading before next stage overwrites
  }

  // epilogue: C/D layout row=(quad*4+reg), col=l15 per 16x16 tile
#pragma unroll
  for (int nt = 0; nt < 4; nt++) {
    const int n = bn0 + wn * 64 + nt * 16 + l15;
    float bv = 0.f;
    if (MODE == 1) bv = bias[n];
#pragma unroll
    for (int mt = 0; mt < 4; mt++) {
      const int mbase = bm0 + wm * 64 + mt * 16 + quad * 4;
#pragma unroll
      for (int r = 0; r < 4; r++) {
        const long m = mbase + r;
        if (MODE == 0) cbf[m * N + n] = (__bf16)acc[mt][nt][r];
        else           cf32[m * N + n] = acc[mt][nt][r] + bv;
      }
    }
  }
}

// ---------------- V transpose: qkv natural layout -> vt[bh][d][s] --------
__global__ __launch_bounds__(256) void transv(const __bf16* __restrict__ qkv,
                                              __bf16* __restrict__ vt) {
  __shared__ __align__(16) __bf16 T[64 * 64];   // [s_local][d]
  const int tid = threadIdx.x, wave = tid >> 6;
  const int bh = blockIdx.x >> 5, st = blockIdx.x & 31;
  const int b = bh >> 4, h = bh & 15;
  const long gbase = (long)(b * Sq + st * 64 + (tid >> 3)) * N1q + h * 192 + 128 + (tid & 7) * 8;
  gl2lds16(qkv + gbase,                 T + wave * 512);
  gl2lds16(qkv + gbase + (long)32 * N1q, T + 2048 + wave * 512);
  __syncthreads();
  const int d = tid >> 2, s4 = (tid & 3) * 16;
  bf16x8 o0, o1;
#pragma unroll
  for (int j = 0; j < 8; j++) o0[j] = T[(s4 + j) * 64 + d];
#pragma unroll
  for (int j = 0; j < 8; j++) o1[j] = T[(s4 + 8 + j) * 64 + d];
  __bf16* dst = vt + (long)(bh * 64 + d) * Sq + st * 64 + s4;
  *(bf16x8*)dst = o0;
  *(bf16x8*)(dst + 8) = o1;
}

// ---------------- flash attention fwd (causal) ---------------------------
// block = (b,h,qt): 4 waves x 16 q-rows = 64-row Q tile; K/V tiles of 64
__global__ __launch_bounds__(256) void attn_fwd(const __bf16* __restrict__ qkv,
                                                const __bf16* __restrict__ vt,
                                                __bf16* __restrict__ aout) {
  __shared__ __align__(16) __bf16 Ks[64 * 64];      // [kcol][d]
  __shared__ __align__(16) __bf16 Vs[64 * 64];      // [d][kcol] (pre-transposed)
  __shared__ __align__(16) __bf16 Ps[4][16 * 72];   // per-wave P, stride 72 (pad)

  const int tid = threadIdx.x;
  const int wave = tid >> 6, lane = tid & 63;
  const int quad = lane >> 4, l15 = lane & 15;
  const int qt = blockIdx.x & 31, bh = blockIdx.x >> 5;
  const int b = bh >> 4, h = bh & 15;
  const int qr0 = qt * 64 + wave * 16;

  // Q fragment (A-layout: m=l15, k=quad*8+j), HD=64 -> 2 chunks of 32
  const long qrow = (long)(b * Sq + qr0 + l15);
  const bf16x8 qf0 = *(const bf16x8*)(qkv + qrow * N1q + h * 192 + quad * 8);
  const bf16x8 qf1 = *(const bf16x8*)(qkv + qrow * N1q + h * 192 + 32 + quad * 8);

  f32x4 oacc[4] = {};
  float m_i[4] = {-1e30f, -1e30f, -1e30f, -1e30f};
  float l_i[4] = {};

  const long kbase = (long)(b * Sq + (tid >> 3)) * N1q + h * 192 + 64 + (tid & 7) * 8;
  const long vbase = (long)(bh * 64 + (tid >> 3)) * Sq + (tid & 7) * 8;

  for (int kt = 0; kt <= qt; kt++) {
    gl2lds16(qkv + kbase + (long)kt * 64 * N1q,            Ks + wave * 512);
    gl2lds16(qkv + kbase + (long)(kt * 64 + 32) * N1q,     Ks + 2048 + wave * 512);
    gl2lds16(vt + vbase + kt * 64,                         Vs + wave * 512);
    gl2lds16(vt + vbase + kt * 64 + (long)32 * Sq,         Vs + 2048 + wave * 512);
    __syncthreads();

    // scores S = Q K^T : D[m=qrow][n=kcol]
    f32x4 sc[4];
#pragma unroll
    for (int nt = 0; nt < 4; nt++) {
      bf16x8 b0 = *(const bf16x8*)&Ks[(nt * 16 + l15) * 64 + quad * 8];
      bf16x8 b1 = *(const bf16x8*)&Ks[(nt * 16 + l15) * 64 + 32 + quad * 8];
      f32x4 z = {};
      z = __builtin_amdgcn_mfma_f32_16x16x32_bf16(qf0, b0, z, 0, 0, 0);
      z = __builtin_amdgcn_mfma_f32_16x16x32_bf16(qf1, b1, z, 0, 0, 0);
      sc[nt] = z;
    }

    const bool diag = (kt == qt);
    float mt4[4] = {-1e30f, -1e30f, -1e30f, -1e30f};
#pragma unroll
    for (int nt = 0; nt < 4; nt++)
#pragma unroll
      for (int r = 0; r < 4; r++) {
        float s = sc[nt][r] * 0.125f;          // HD^-0.5
        if (diag && (kt * 64 + nt * 16 + l15 > qr0 + quad * 4 + r)) s = -1e30f;
        sc[nt][r] = s;
        mt4[r] = fmaxf(mt4[r], s);
      }
    // row max across the 16 lanes holding this row
#pragma unroll
    for (int off = 8; off; off >>= 1)
#pragma unroll
      for (int r = 0; r < 4; r++) mt4[r] = fmaxf(mt4[r], __shfl_xor(mt4[r], off));

    float alpha[4];
#pragma unroll
    for (int r = 0; r < 4; r++) {
      float mn = fmaxf(m_i[r], mt4[r]);
      alpha[r] = __expf(m_i[r] - mn);
      m_i[r] = mn;
    }
    float rs[4] = {};
#pragma unroll
    for (int nt = 0; nt < 4; nt++)
#pragma unroll
      for (int r = 0; r < 4; r++) {
        float p = __expf(sc[nt][r] - m_i[r]);
        sc[nt][r] = p;
        rs[r] += p;
      }
#pragma unroll
    for (int off = 8; off; off >>= 1)
#pragma unroll
      for (int r = 0; r < 4; r++) rs[r] += __shfl_xor(rs[r], off);
#pragma unroll
    for (int r = 0; r < 4; r++) l_i[r] = l_i[r] * alpha[r] + rs[r];
#pragma unroll
    for (int nt = 0; nt < 4; nt++)
#pragma unroll
      for (int r = 0; r < 4; r++) oacc[nt][r] *= alpha[r];

    // P: C-layout -> LDS -> A-layout (per-wave region, no barrier needed)
#pragma unroll
    for (int nt = 0; nt < 4; nt++)
#pragma unroll
      for (int r = 0; r < 4; r++)
        Ps[wave][(quad * 4 + r) * 72 + nt * 16 + l15] = (__bf16)sc[nt][r];

#pragma unroll
    for (int c = 0; c < 2; c++) {
      bf16x8 af = *(const bf16x8*)&Ps[wave][l15 * 72 + c * 32 + quad * 8];
#pragma unroll
      for (int nt = 0; nt < 4; nt++) {
        bf16x8 bv = *(const bf16x8*)&Vs[(nt * 16 + l15) * 64 + c * 32 + quad * 8];
        oacc[nt] = __builtin_amdgcn_mfma_f32_16x16x32_bf16(af, bv, oacc[nt], 0, 0, 0);
      }
    }
    __syncthreads();   // before next tile overwrites Ks/Vs
  }

  // epilogue: O /= l, write bf16 attn-out in (b,s,h*64+d) layout
#pragma unroll
  for (int r = 0; r < 4; r++) {
    const float inv = 1.0f / l_i[r];
    const int row = qr0 + quad * 4 + r;
#pragma unroll
    for (int nt = 0; nt < 4; nt++) {
      float v = oacc[nt][r] * inv;
      aout[(long)(b * Sq + row) * Eq + h * 64 + nt * 16 + l15] = (__bf16)v;
    }
  }
}

// ---------------- launch ----------------
extern "C" void kernel_launch(void* const* d_in, const int* in_sizes, int n_in,
                              void* d_out, int out_size, void* d_ws, size_t ws_size,
                              hipStream_t stream) {
  const float* x      = (const float*)d_in[0];
  const float* w_qkv  = (const float*)d_in[1];
  const float* w_proj = (const float*)d_in[2];
  const float* b_proj = (const float*)d_in[3];
  float* out = (float*)d_out;

  char* w = (char*)d_ws;
  __bf16* xb     = (__bf16*)w; w += (size_t)Mq * Kq * 2;        // 16.8 MB
  __bf16* wqkvb  = (__bf16*)w; w += (size_t)N1q * Kq * 2;       //  6.3 MB
  __bf16* wprojb = (__bf16*)w; w += (size_t)Eq * Kq * 2;        //  2.1 MB
  __bf16* qkvb   = (__bf16*)w; w += (size_t)Mq * N1q * 2;       // 50.3 MB
  __bf16* vtb    = (__bf16*)w; w += (size_t)Bq * Hq * HDq * Sq * 2; // 16.8 MB
  __bf16* attnb  = (__bf16*)w;                                   // 16.8 MB

  cvt4<<<(Mq * Kq / 4 + 255) / 256, 256, 0, stream>>>(x, xb, Mq * Kq / 4);
  cvt4<<<(N1q * Kq / 4 + 255) / 256, 256, 0, stream>>>(w_qkv, wqkvb, N1q * Kq / 4);
  cvt4<<<(Eq * Kq / 4 + 255) / 256, 256, 0, stream>>>(w_proj, wprojb, Eq * Kq / 4);

  gemm_bt<0><<<dim3(Mq / 128, N1q / 128), 256, 0, stream>>>(xb, wqkvb, N1q, Kq, qkvb, nullptr, nullptr);

  transv<<<Bq * Hq * (Sq / 64), 256, 0, stream>>>(qkvb, vtb);

  attn_fwd<<<Bq * Hq * (Sq / 64), 256, 0, stream>>>(qkvb, vtb, attnb);

  gemm_bt<1><<<dim3(Mq / 128, Eq / 128), 256, 0, stream>>>(attnb, wprojb, Eq, Kq, nullptr, b_proj, out);
}